// Round 18
// baseline (48.545 us; speedup 1.0000x reference)
//
#include <hip/hip_runtime.h>
#include <math.h>

#define NPTS 1024
#define THREADS 256   // 4 waves; TWO independent batches per block (2 waves each)

typedef float v2f __attribute__((ext_vector_type(2)));
typedef int v2i __attribute__((ext_vector_type(2)));

static __device__ __forceinline__ v2f b2(float s) { return (v2f){s, s}; }
static __device__ __forceinline__ v2f vabs2(v2f v) {
  v2i u = __builtin_bit_cast(v2i, v);
  u &= (v2i){0x7fffffff, 0x7fffffff};
  return __builtin_bit_cast(v2f, u);
}

template <int CTRL>
__device__ __forceinline__ float dpp_add(float v) {
  int m = __builtin_amdgcn_update_dpp(0, __builtin_bit_cast(int, v), CTRL, 0xF, 0xF, true);
  return v + __builtin_bit_cast(float, m);
}

// 4-step reduction within rows of 16: lanes 15,31,47,63 hold their row sums
__device__ __forceinline__ float row_red16(float v) {
  v = dpp_add<0x111>(v);  // row_shr:1
  v = dpp_add<0x112>(v);  // row_shr:2
  v = dpp_add<0x114>(v);  // row_shr:4
  v = dpp_add<0x118>(v);  // row_shr:8
  return v;
}

__device__ __forceinline__ float rl_f32(float v, int l) {
  return __builtin_bit_cast(float,
      __builtin_amdgcn_readlane(__builtin_bit_cast(int, v), l));
}

__device__ __forceinline__ float bperm_f(int srclane, float v) {
  return __builtin_bit_cast(float,
      __builtin_amdgcn_ds_bpermute(srclane << 2, __builtin_bit_cast(int, v)));
}

__device__ __forceinline__ float fast_rsq(float x) {
#if __has_builtin(__builtin_amdgcn_rsqf)
  return __builtin_amdgcn_rsqf(x);
#else
  return 1.0f / sqrtf(x);
#endif
}

__device__ __forceinline__ float rcp_nr(float d) {
#if __has_builtin(__builtin_amdgcn_rcpf)
  float r = __builtin_amdgcn_rcpf(d);
  return r * (2.0f - d * r);   // one Newton step -> ~0.5 ulp
#else
  return 1.0f / d;
#endif
}

// packed accumulation of one float2-pair of points into the 38 moments
__device__ __forceinline__ void acc_pair(v2f M2[28], v2f Z2[10],
                                         v2f x, v2f y, v2f w, v2f z) {
  v2f wz = w * z;
  v2f y1 = y, y2 = y * y, y3 = y2 * y, y4 = y3 * y, y5 = y4 * y, y6 = y5 * y;
  v2f tx = w;
  M2[0] += tx;          M2[1] += tx * y1; M2[2] += tx * y2; M2[3] += tx * y3;
  M2[4] += tx * y4;     M2[5] += tx * y5; M2[6] += tx * y6;
  tx *= x;
  M2[7] += tx;          M2[8] += tx * y1; M2[9] += tx * y2; M2[10] += tx * y3;
  M2[11] += tx * y4;    M2[12] += tx * y5;
  tx *= x;
  M2[13] += tx;         M2[14] += tx * y1; M2[15] += tx * y2; M2[16] += tx * y3;
  M2[17] += tx * y4;
  tx *= x;
  M2[18] += tx;         M2[19] += tx * y1; M2[20] += tx * y2; M2[21] += tx * y3;
  tx *= x;
  M2[22] += tx;         M2[23] += tx * y1; M2[24] += tx * y2;
  tx *= x;
  M2[25] += tx;         M2[26] += tx * y1;
  tx *= x;
  M2[27] += tx;
  v2f tz = wz;
  Z2[0] += tz;          Z2[1] += tz * y1; Z2[2] += tz * y2; Z2[3] += tz * y3;
  tz *= x;
  Z2[4] += tz;          Z2[5] += tz * y1; Z2[6] += tz * y2;
  tz *= x;
  Z2[7] += tz;          Z2[8] += tz * y1;
  tz *= x;
  Z2[9] += tz;
}

__global__ void __launch_bounds__(THREADS) deepfit_kernel(
    const float* __restrict__ pts, const float* __restrict__ wts,
    float* __restrict__ beta_out, float* __restrict__ nest_out,
    float* __restrict__ nn_out, int B)
{
  const int t = threadIdx.x;
  const int lane = t & 63;
  const int wid = t >> 6;
  const int half = wid >> 1;    // which of the two batches in this block
  const int hwid = wid & 1;     // wave index within the half (0 = solver wave)
  const int th = t & 127;       // thread index within the half
  int b = blockIdx.x * 2 + half;
  if (b >= B) b = B - 1;        // odd-B clamp: duplicate last batch (identical writes)

  // per-half LDS slices; combine reads s_red[half][j][lane] conflict-free
  __shared__ float s_red[2][8][40];   // col 0..37 = moments, col 39 = habs
  __shared__ int s_cnt[2][2];
  __shared__ float s_Lf[2][100];
  __shared__ float s_bh[2][11];       // beta[0..9], mh

  const float4* px4 = reinterpret_cast<const float4*>(pts + (size_t)b * (3 * NPTS));
  const float4* pw4 = reinterpret_cast<const float4*>(wts + (size_t)b * NPTS);

  // ---- load 8 pts/thread (2 float4 chunks); x,y held for the normals pass ----
  float4 xc[2], yc[2], zc[2], wc[2];
#pragma unroll
  for (int c = 0; c < 2; ++c) {
    xc[c] = px4[th + 128 * c];
    yc[c] = px4[256 + th + 128 * c];
    zc[c] = px4[512 + th + 128 * c];
    wc[c] = pw4[th + 128 * c];
  }

  const int part = hwid * 4 + (lane >> 4);   // this 16-lane group's partial slot

  // ---- h partial + valid count (col 39 written once, survives redo) ----
  v2f hab2 = b2(0.f);
  int cnt = 0;
#pragma unroll
  for (int c = 0; c < 2; ++c) {
    v2f xq[2] = {{xc[c].x, xc[c].y}, {xc[c].z, xc[c].w}};
    v2f yq[2] = {{yc[c].x, yc[c].y}, {yc[c].z, yc[c].w}};
    hab2 += vabs2(xq[0]) + vabs2(yq[0]) + vabs2(xq[1]) + vabs2(yq[1]);
    cnt += (int)__popcll(__ballot(wc[c].x > 0.001f));
    cnt += (int)__popcll(__ballot(wc[c].y > 0.001f));
    cnt += (int)__popcll(__ballot(wc[c].z > 0.001f));
    cnt += (int)__popcll(__ballot(wc[c].w > 0.001f));
  }
  {
    float habs = row_red16(hab2.x + hab2.y);
    if ((lane & 15) == 15) s_red[half][part][39] = habs;
    if (lane == 0) s_cnt[half][hwid] = cnt;
  }

  // ---- moments (packed float2): 28 of w*x^a*y^b (a+b<=6) + 10 of w*z*x^a*y^b
  //      (a+b<=3), RAW coords (h cancels exactly in beta). Optimistic w. ----
  float momvec = 0.f;   // valid in solver wave (hwid==0) after the loop
  bool wone = false;    // per-half redo flag
  for (int it = 0; it < 2; ++it) {
    if (it == 1) __syncthreads();  // protect s_red rewrite on redo path
    v2f M2[28], Z2[10];
#pragma unroll
    for (int i = 0; i < 28; ++i) M2[i] = b2(0.f);
#pragma unroll
    for (int i = 0; i < 10; ++i) Z2[i] = b2(0.f);

#pragma unroll
    for (int c = 0; c < 2; ++c) {
      v2f xq[2] = {{xc[c].x, xc[c].y}, {xc[c].z, xc[c].w}};
      v2f yq[2] = {{yc[c].x, yc[c].y}, {yc[c].z, yc[c].w}};
      v2f zq[2] = {{zc[c].x, zc[c].y}, {zc[c].z, zc[c].w}};
      v2f wq[2] = {{wc[c].x, wc[c].y}, {wc[c].z, wc[c].w}};
#pragma unroll
      for (int q = 0; q < 2; ++q) {
        v2f w = wone ? b2(1.0f) : wq[q];
        acc_pair(M2, Z2, xq[q], yq[q], w, zq[q]);
      }
    }

    // horizontal + 16-lane-row reduce + publish (8 slots per half)
#pragma unroll
    for (int i = 0; i < 28; ++i) {
      float v = row_red16(M2[i].x + M2[i].y);
      if ((lane & 15) == 15) s_red[half][part][i] = v;
    }
#pragma unroll
    for (int i = 0; i < 10; ++i) {
      float v = row_red16(Z2[i].x + Z2[i].y);
      if ((lane & 15) == 15) s_red[half][part][28 + i] = v;
    }
    __syncthreads();  // B1: partials published (both halves)

    // ---- solver wave of each half combines its partial-columns ----
    if (hwid == 0 && lane < 40) {
      float acc = 0.f;
#pragma unroll
      for (int j = 0; j < 8; ++j) acc += s_red[half][j][lane];
      momvec = acc;
    }
    // block-uniform loop control; per-half weights decision
    int ctot_own = s_cnt[half][0] + s_cnt[half][1];
    int ctot_oth = s_cnt[half ^ 1][0] + s_cnt[half ^ 1][1];
    bool any_redo = (ctot_own <= 18) || (ctot_oth <= 18);
    if (it == 1 || !any_redo) break;
    wone = (ctot_own <= 18);  // other half recomputes with original w (idempotent)
  }

  // ---- solver wave (hwid==0): gather raw XtX row + rhs, f32 LDL^T, publish ----
  if (hwid == 0) {
    float mh;
    {
      float htot = rl_f32(momvec, 39);
      mh = htot * (1.0f / 2048.0f);  // (mean|x| + mean|y|)/2
      if (fabsf(mh) < 1e-4f) mh = 0.1f;
    }
    const int lc = (lane < 10) ? lane : 0;
    const int axi = (0x18D21u >> (2 * lc)) & 3;  // x-exp of {x,y,x2,y2,xy,x3,y3,x2y,xy2,1}
    const int ayi = (0x27184u >> (2 * lc)) & 3;  // y-exp
    constexpr int AXC[10] = {1, 0, 2, 0, 1, 3, 0, 2, 1, 0};
    constexpr int AYC[10] = {0, 1, 0, 2, 1, 0, 3, 1, 2, 0};
    float a[10], yy;
#pragma unroll
    for (int j = 0; j < 10; ++j) {
      int as = axi + AXC[j];
      int bs = ayi + AYC[j];
      int idx = as * 7 - (as * (as - 1)) / 2 + bs;  // moment index, a+b<=6
      a[j] = bperm_f(idx, momvec);
    }
    {
      int zi = axi * 4 - (axi * (axi - 1)) / 2 + ayi;  // z-moment index, a+b<=3
      yy = bperm_f(28 + zi, momvec);
    }

    float bf = 0.f;
    if (lane < 10) {
      float rd_own = 1.0f;
#pragma unroll
      for (int j = 0; j < 10; ++j) {
        float dj = rl_f32(a[j], j);
        float rdj = rcp_nr(dj);
        float lij = a[j] * rdj;          // L[i][j] for i>j
        s_Lf[half][lane * 10 + j] = lij; // waited before back solve
        if (lane == j) rd_own = rdj;
        float wj = rl_f32(yy, j);
        if (lane > j) yy -= lij * wj;  // forward solve L w = y
#pragma unroll
        for (int k = j + 1; k < 10; ++k) {
          float ajk = rl_f32(a[k], j);  // A[j][k] at lane j
          a[k] -= lij * ajk;            // trailing update
        }
      }
      yy *= rd_own;  // apply D^{-1}
      asm volatile("s_waitcnt lgkmcnt(0)" ::: "memory");  // same-wave DS in-order
      __builtin_amdgcn_sched_barrier(0);
#pragma unroll
      for (int j = 9; j >= 0; --j) {  // back solve L^T beta = v (unit diag)
        float xj = rl_f32(yy, j);
        if (lane < j) yy -= s_Lf[half][j * 10 + lane] * xj;
      }
      bf = yy;  // raw solve IS final beta (h cancels)
      s_bh[half][lane] = bf;
      beta_out[(size_t)b * 10 + lane] = bf;
    }
    if (lane == 0) {
      s_bh[half][10] = mh;
      float b0 = rl_f32(bf, 0);
      float b1 = rl_f32(bf, 1);
      float invn = fast_rsq(b0 * b0 + b1 * b1 + 1.0f);
      nest_out[(size_t)b * 3 + 0] = -b0 * invn;
      nest_out[(size_t)b * 3 + 1] = -b1 * invn;
      nest_out[(size_t)b * 3 + 2] = invn;
    }
  }
  __syncthreads();  // B2: beta + mh published (both halves)

  // ---- all threads: read own half's beta/mh, fold 1/h into coefficients ----
  float bb[10];
#pragma unroll
  for (int j = 0; j < 10; ++j) bb[j] = s_bh[half][j];
  const float mh = s_bh[half][10];
  const float ih = 1.0f / mh;
  const float ih2 = ih * ih;
  const float u0 = bb[0], u2 = 2.f * bb[2] * ih, u4 = bb[4] * ih;
  const float u5 = 3.f * bb[5] * ih2, u7 = 2.f * bb[7] * ih2, u8 = bb[8] * ih2;
  const float v1 = bb[1], v3 = 2.f * bb[3] * ih, v4 = bb[4] * ih;
  const float v6 = 3.f * bb[6] * ih2, v7 = bb[7] * ih2, v8 = 2.f * bb[8] * ih2;

  // ---- normals, packed pairs (raw coords; 1/h folded into coeffs) ----
  float4* o4 = reinterpret_cast<float4*>(nn_out + (size_t)b * (NPTS * 3));
#pragma unroll
  for (int c = 0; c < 2; ++c) {
    v2f xq[2] = {{xc[c].x, xc[c].y}, {xc[c].z, xc[c].w}};
    v2f yq[2] = {{yc[c].x, yc[c].y}, {yc[c].z, yc[c].w}};
    float nx[4], ny[4], nz[4];
#pragma unroll
    for (int q = 0; q < 2; ++q) {
      v2f x = xq[q], y = yq[q];
      v2f x2 = x * x, y2 = y * y, xy = x * y;
      v2f sx = b2(u0) + b2(u2) * x + b2(u4) * y + b2(u5) * x2 + b2(u7) * xy + b2(u8) * y2;
      v2f sy = b2(v1) + b2(v3) * y + b2(v4) * x + b2(v6) * y2 + b2(v7) * x2 + b2(v8) * xy;
      v2f vx = -sx, vy = -sy;
      v2f n2 = vx * vx + vy * vy + b2(1.0f);
      float i0 = fast_rsq(n2.x), i1 = fast_rsq(n2.y);
      nx[2 * q + 0] = vx.x * i0; ny[2 * q + 0] = vy.x * i0; nz[2 * q + 0] = i0;
      nx[2 * q + 1] = vx.y * i1; ny[2 * q + 1] = vy.y * i1; nz[2 * q + 1] = i1;
    }
    int base = 3 * (th + 128 * c);
    o4[base + 0] = make_float4(nx[0], ny[0], nz[0], nx[1]);
    o4[base + 1] = make_float4(ny[1], nz[1], nx[2], ny[2]);
    o4[base + 2] = make_float4(nz[2], nx[3], ny[3], nz[3]);
  }
}

extern "C" void kernel_launch(void* const* d_in, const int* in_sizes, int n_in,
                              void* d_out, int out_size, void* d_ws, size_t ws_size,
                              hipStream_t stream) {
  const float* pts = (const float*)d_in[0];
  const float* wts = (const float*)d_in[1];
  float* out = (float*)d_out;
  const int B = in_sizes[1] / NPTS;
  float* beta_out = out;
  float* nest_out = out + (size_t)B * 10;
  float* nn_out = out + (size_t)B * 13;
  const int grid = (B + 1) / 2;
  deepfit_kernel<<<grid, THREADS, 0, stream>>>(pts, wts, beta_out, nest_out, nn_out, B);
}

// Round 19
// 45.187 us; speedup vs baseline: 1.0743x; 1.0743x over previous
//
#include <hip/hip_runtime.h>
#include <math.h>

#define NPTS 1024
#define THREADS 256

typedef float v2f __attribute__((ext_vector_type(2)));
typedef int v2i __attribute__((ext_vector_type(2)));

static __device__ __forceinline__ v2f b2(float s) { return (v2f){s, s}; }
static __device__ __forceinline__ v2f vabs2(v2f v) {
  v2i u = __builtin_bit_cast(v2i, v);
  u &= (v2i){0x7fffffff, 0x7fffffff};
  return __builtin_bit_cast(v2f, u);
}

template <int CTRL>
__device__ __forceinline__ float dpp_add(float v) {
  int m = __builtin_amdgcn_update_dpp(0, __builtin_bit_cast(int, v), CTRL, 0xF, 0xF, true);
  return v + __builtin_bit_cast(float, m);
}

// 4-step reduction within rows of 16: lanes 15,31,47,63 hold their row sums
__device__ __forceinline__ float row_red16(float v) {
  v = dpp_add<0x111>(v);  // row_shr:1
  v = dpp_add<0x112>(v);  // row_shr:2
  v = dpp_add<0x114>(v);  // row_shr:4
  v = dpp_add<0x118>(v);  // row_shr:8
  return v;
}

__device__ __forceinline__ float rl_f32(float v, int l) {
  return __builtin_bit_cast(float,
      __builtin_amdgcn_readlane(__builtin_bit_cast(int, v), l));
}

__device__ __forceinline__ float bperm_f(int srclane, float v) {
  return __builtin_bit_cast(float,
      __builtin_amdgcn_ds_bpermute(srclane << 2, __builtin_bit_cast(int, v)));
}

__device__ __forceinline__ float fast_rsq(float x) {
#if __has_builtin(__builtin_amdgcn_rsqf)
  return __builtin_amdgcn_rsqf(x);
#else
  return 1.0f / sqrtf(x);
#endif
}

__device__ __forceinline__ float rcp_nr(float d) {
#if __has_builtin(__builtin_amdgcn_rcpf)
  float r = __builtin_amdgcn_rcpf(d);
  return r * (2.0f - d * r);   // one Newton step -> ~0.5 ulp
#else
  return 1.0f / d;
#endif
}

__global__ void __launch_bounds__(THREADS) deepfit_kernel(
    const float* __restrict__ pts, const float* __restrict__ wts,
    float* __restrict__ beta_out, float* __restrict__ nest_out,
    float* __restrict__ nn_out)
{
  const int b = blockIdx.x;
  const int t = threadIdx.x;
  const int lane = t & 63;
  const int wid = t >> 6;

  // partial-slot-major: wave-0 combine reads s_red[j][lane] conflict-free
  __shared__ float s_red[16][40];   // col 0..37 = moments, col 39 = habs
  __shared__ int s_cnt[4];
  __shared__ float s_Lf[100];       // wave-0 f32 transpose buffer for back solve
  __shared__ float s_bh[11];        // beta[0..9], mh

  const float4* px4 = reinterpret_cast<const float4*>(pts + (size_t)b * (3 * NPTS));
  const float4* pw4 = reinterpret_cast<const float4*>(wts + (size_t)b * NPTS);

  float4 lx4 = px4[t];
  float4 ly4 = px4[THREADS + t];
  float4 lz4 = px4[2 * THREADS + t];
  float4 lw4 = pw4[t];

  // pairs for packed (v_pk_*) math
  v2f xp[2] = {{lx4.x, lx4.y}, {lx4.z, lx4.w}};
  v2f yq[2] = {{ly4.x, ly4.y}, {ly4.z, ly4.w}};
  v2f zp[2] = {{lz4.x, lz4.y}, {lz4.z, lz4.w}};
  v2f wp[2] = {{lw4.x, lw4.y}, {lw4.z, lw4.w}};

  const int part = wid * 4 + (lane >> 4);   // this 16-lane group's partial slot

  // ---- h partial + valid count (written once; col 39 survives redo rewrite) ----
  v2f hab2 = vabs2(xp[0]) + vabs2(yq[0]) + vabs2(xp[1]) + vabs2(yq[1]);
  int cnt = 0;
  cnt += (int)__popcll(__ballot(lw4.x > 0.001f));
  cnt += (int)__popcll(__ballot(lw4.y > 0.001f));
  cnt += (int)__popcll(__ballot(lw4.z > 0.001f));
  cnt += (int)__popcll(__ballot(lw4.w > 0.001f));
  {
    float habs = row_red16(hab2.x + hab2.y);
    if ((lane & 15) == 15) s_red[part][39] = habs;
    if (lane == 0) s_cnt[wid] = cnt;
  }

  // ---- moments (packed float2): 28 of w*x^a*y^b (a+b<=6) + 10 of w*z*x^a*y^b
  //      (a+b<=3), RAW coords (h cancels exactly in beta). Optimistic w. ----
  float momvec = 0.f;   // valid in wave 0 only after the loop
  bool wone = false;
  for (int it = 0; it < 2; ++it) {
    if (it == 1) __syncthreads();  // protect s_red rewrite on redo path
    v2f M2[28], Z2[10];
#pragma unroll
    for (int i = 0; i < 28; ++i) M2[i] = b2(0.f);
#pragma unroll
    for (int i = 0; i < 10; ++i) Z2[i] = b2(0.f);

#pragma unroll
    for (int q = 0; q < 2; ++q) {
      v2f x = xp[q], y = yq[q];
      v2f w = wone ? b2(1.0f) : wp[q];
      v2f wz = w * zp[q];
      v2f y1 = y, y2 = y * y, y3 = y2 * y, y4 = y3 * y, y5 = y4 * y, y6 = y5 * y;
      v2f tx = w;
      M2[0] += tx;          M2[1] += tx * y1; M2[2] += tx * y2; M2[3] += tx * y3;
      M2[4] += tx * y4;     M2[5] += tx * y5; M2[6] += tx * y6;
      tx *= x;
      M2[7] += tx;          M2[8] += tx * y1; M2[9] += tx * y2; M2[10] += tx * y3;
      M2[11] += tx * y4;    M2[12] += tx * y5;
      tx *= x;
      M2[13] += tx;         M2[14] += tx * y1; M2[15] += tx * y2; M2[16] += tx * y3;
      M2[17] += tx * y4;
      tx *= x;
      M2[18] += tx;         M2[19] += tx * y1; M2[20] += tx * y2; M2[21] += tx * y3;
      tx *= x;
      M2[22] += tx;         M2[23] += tx * y1; M2[24] += tx * y2;
      tx *= x;
      M2[25] += tx;         M2[26] += tx * y1;
      tx *= x;
      M2[27] += tx;
      v2f tz = wz;
      Z2[0] += tz;          Z2[1] += tz * y1; Z2[2] += tz * y2; Z2[3] += tz * y3;
      tz *= x;
      Z2[4] += tz;          Z2[5] += tz * y1; Z2[6] += tz * y2;
      tz *= x;
      Z2[7] += tz;          Z2[8] += tz * y1;
      tz *= x;
      Z2[9] += tz;
    }

    // horizontal + 16-lane-row reduce + publish
#pragma unroll
    for (int i = 0; i < 28; ++i) {
      float v = row_red16(M2[i].x + M2[i].y);
      if ((lane & 15) == 15) s_red[part][i] = v;
    }
#pragma unroll
    for (int i = 0; i < 10; ++i) {
      float v = row_red16(Z2[i].x + Z2[i].y);
      if ((lane & 15) == 15) s_red[part][28 + i] = v;
    }
    __syncthreads();  // B1: partials published

    // ---- wave 0 only: combine partial-columns ----
    if (wid == 0 && lane < 40) {
      float acc = 0.f;
#pragma unroll
      for (int j = 0; j < 16; ++j) acc += s_red[j][lane];
      momvec = acc;
    }
    int ctot = s_cnt[0] + s_cnt[1] + s_cnt[2] + s_cnt[3];
    if (it == 1 || ctot > 18) break;
    wone = true;  // block-uniform redo with w=1 (essentially never)
  }

  // ---- wave 0: gather row `lane` of raw XtX + rhs, f32 LDL^T solve, publish ----
  if (wid == 0) {
    float mh;
    {
      float htot = rl_f32(momvec, 39);
      mh = htot * (1.0f / 2048.0f);  // (mean|x| + mean|y|)/2
      if (fabsf(mh) < 1e-4f) mh = 0.1f;
    }
    const int lc = (lane < 10) ? lane : 0;
    const int axi = (0x18D21u >> (2 * lc)) & 3;  // x-exp of {x,y,x2,y2,xy,x3,y3,x2y,xy2,1}
    const int ayi = (0x27184u >> (2 * lc)) & 3;  // y-exp
    constexpr int AXC[10] = {1, 0, 2, 0, 1, 3, 0, 2, 1, 0};
    constexpr int AYC[10] = {0, 1, 0, 2, 1, 0, 3, 1, 2, 0};
    float a[10], yy;
#pragma unroll
    for (int j = 0; j < 10; ++j) {
      int as = axi + AXC[j];
      int bs = ayi + AYC[j];
      int idx = as * 7 - (as * (as - 1)) / 2 + bs;  // moment index, a+b<=6
      a[j] = bperm_f(idx, momvec);
    }
    {
      int zi = axi * 4 - (axi * (axi - 1)) / 2 + ayi;  // z-moment index, a+b<=3
      yy = bperm_f(28 + zi, momvec);
    }

    float bf = 0.f;
    if (lane < 10) {
      float rd_own = 1.0f;
#pragma unroll
      for (int j = 0; j < 10; ++j) {
        float dj = rl_f32(a[j], j);
        float rdj = rcp_nr(dj);
        float lij = a[j] * rdj;    // L[i][j] for i>j
        s_Lf[lane * 10 + j] = lij; // waited before back solve
        if (lane == j) rd_own = rdj;
        float wj = rl_f32(yy, j);
        if (lane > j) yy -= lij * wj;  // forward solve L w = y
#pragma unroll
        for (int k = j + 1; k < 10; ++k) {
          float ajk = rl_f32(a[k], j);  // A[j][k] at lane j
          a[k] -= lij * ajk;            // trailing update
        }
      }
      yy *= rd_own;  // apply D^{-1}
      asm volatile("s_waitcnt lgkmcnt(0)" ::: "memory");  // same-wave DS in-order
      __builtin_amdgcn_sched_barrier(0);
#pragma unroll
      for (int j = 9; j >= 0; --j) {  // back solve L^T beta = v (unit diag)
        float xj = rl_f32(yy, j);
        if (lane < j) yy -= s_Lf[j * 10 + lane] * xj;
      }
      bf = yy;  // raw solve IS final beta (h cancels)
      s_bh[lane] = bf;
      beta_out[(size_t)b * 10 + lane] = bf;
    }
    if (lane == 0) {
      s_bh[10] = mh;
      float b0 = rl_f32(bf, 0);
      float b1 = rl_f32(bf, 1);
      float invn = fast_rsq(b0 * b0 + b1 * b1 + 1.0f);
      nest_out[(size_t)b * 3 + 0] = -b0 * invn;
      nest_out[(size_t)b * 3 + 1] = -b1 * invn;
      nest_out[(size_t)b * 3 + 2] = invn;
    }
  }
  __syncthreads();  // B2: beta + mh published

  // ---- all threads: read beta/mh (LDS broadcast), fold 1/h into coefficients ----
  float bb[10];
#pragma unroll
  for (int j = 0; j < 10; ++j) bb[j] = s_bh[j];
  const float mh = s_bh[10];
  const float ih = 1.0f / mh;
  const float ih2 = ih * ih;
  const float u0 = bb[0], u2 = 2.f * bb[2] * ih, u4 = bb[4] * ih;
  const float u5 = 3.f * bb[5] * ih2, u7 = 2.f * bb[7] * ih2, u8 = bb[8] * ih2;
  const float v1 = bb[1], v3 = 2.f * bb[3] * ih, v4 = bb[4] * ih;
  const float v6 = 3.f * bb[6] * ih2, v7 = bb[7] * ih2, v8 = 2.f * bb[8] * ih2;

  // ---- normals, packed pairs (raw coords; 1/h folded into coeffs) ----
  float nx[4], ny[4], nz[4];
#pragma unroll
  for (int q = 0; q < 2; ++q) {
    v2f x = xp[q], y = yq[q];
    v2f x2 = x * x, y2 = y * y, xy = x * y;
    v2f sx = b2(u0) + b2(u2) * x + b2(u4) * y + b2(u5) * x2 + b2(u7) * xy + b2(u8) * y2;
    v2f sy = b2(v1) + b2(v3) * y + b2(v4) * x + b2(v6) * y2 + b2(v7) * x2 + b2(v8) * xy;
    v2f vx = -sx, vy = -sy;
    v2f n2 = vx * vx + vy * vy + b2(1.0f);
    float i0 = fast_rsq(n2.x), i1 = fast_rsq(n2.y);
    nx[2 * q + 0] = vx.x * i0; ny[2 * q + 0] = vy.x * i0; nz[2 * q + 0] = i0;
    nx[2 * q + 1] = vx.y * i1; ny[2 * q + 1] = vy.y * i1; nz[2 * q + 1] = i1;
  }
  {
    float4* o4 = reinterpret_cast<float4*>(nn_out + (size_t)b * (NPTS * 3));
    float4 f0 = make_float4(nx[0], ny[0], nz[0], nx[1]);
    float4 f1 = make_float4(ny[1], nz[1], nx[2], ny[2]);
    float4 f2 = make_float4(nz[2], nx[3], ny[3], nz[3]);
    o4[3 * t + 0] = f0;
    o4[3 * t + 1] = f1;
    o4[3 * t + 2] = f2;
  }
}

extern "C" void kernel_launch(void* const* d_in, const int* in_sizes, int n_in,
                              void* d_out, int out_size, void* d_ws, size_t ws_size,
                              hipStream_t stream) {
  const float* pts = (const float*)d_in[0];
  const float* wts = (const float*)d_in[1];
  float* out = (float*)d_out;
  const int B = in_sizes[1] / NPTS;
  float* beta_out = out;
  float* nest_out = out + (size_t)B * 10;
  float* nn_out = out + (size_t)B * 13;
  deepfit_kernel<<<B, THREADS, 0, stream>>>(pts, wts, beta_out, nest_out, nn_out);
}